// Round 11
// baseline (168.480 us; speedup 1.0000x reference)
//
#include <hip/hip_runtime.h>
#include <math.h>

#define HH 512
#define WW 1024
#define HWSZ (HH*WW)
#define BB 4
#define KSIG 11.541560327111707
#define DD_OFF (BB*3*HWSZ)
#define DCLAMP 16777216.0f   /* 2^24: den>=2^24 -> w<=6e-8 (negligible), keeps quad product finite */

typedef float v2f __attribute__((ext_vector_type(2)));

// ---- pair-eval (2 evals, 2 rcp) -- used only for leftover odd pairs.
#define PEVAL(P, MI) {                                                        \
    const float4 t = tp[(MI)*7];           /* (D0,D1,C0,C1) */                \
    v2f den = (v2f){t.z, t.w} * rc + rr;   /* v_pk_fma_f32 */                 \
    v2f w = { __builtin_amdgcn_rcpf(den.x),                                   \
              __builtin_amdgcn_rcpf(den.y) };                                 \
    aW##P += w;                                                               \
    aR##P += w * v0;  aG##P += w * v1;  aB##P += w * v2;                      \
    v2f cand = { r >= t.x ? di : -1e30f,                                      \
                 r >= t.y ? di : -1e30f };                                    \
    aD##P = __builtin_elementwise_max(aD##P, cand);                           \
}

// ---- quad-eval (4 evals, ONE rcp): w_i = ip * (product of other three dens)
// dens clamped to <=2^24 so p=d0d1d2d3 <= 2^96 (finite); reconstruction via
// packed half-swapped muls. Sentinel halves: den=inf->2^24 -> w=6e-8 ~ 0.
#define QEVAL(PA, PB, MIA, MIB) {                                             \
    const float4 ta = tp[(MIA)*7];                                            \
    const float4 tb = tp[(MIB)*7];                                            \
    v2f dA = (v2f){ta.z, ta.w} * rc + rr;  /* {d0,d1} */                      \
    v2f dB = (v2f){tb.z, tb.w} * rc + rr;  /* {d2,d3} */                      \
    dA.x = fminf(dA.x, DCLAMP); dA.y = fminf(dA.y, DCLAMP);                   \
    dB.x = fminf(dB.x, DCLAMP); dB.y = fminf(dB.y, DCLAMP);                   \
    const v2f pm = dA * dB;                /* {d0d2, d1d3} */                 \
    const float ip = __builtin_amdgcn_rcpf(pm.x * pm.y);   /* 1/(d0d1d2d3) */ \
    const v2f sw = (v2f){pm.y, pm.x};                                         \
    const v2f wA = (sw * dB) * ip;         /* {d1d2d3, d0d2d3}*ip = {1/d0,1/d1} */ \
    const v2f wB = (sw * dA) * ip;         /* {d0d1d3, d0d1d2}*ip = {1/d2,1/d3} */ \
    aW##PA += wA;                                                             \
    aR##PA += wA * v0;  aG##PA += wA * v1;  aB##PA += wA * v2;                \
    aW##PB += wB;                                                             \
    aR##PB += wB * v0;  aG##PB += wB * v1;  aB##PB += wB * v2;                \
    v2f cA = { r >= ta.x ? di : -1e30f,                                       \
               r >= ta.y ? di : -1e30f };                                     \
    v2f cB = { r >= tb.x ? di : -1e30f,                                       \
               r >= tb.y ? di : -1e30f };                                     \
    aD##PA = __builtin_elementwise_max(aD##PA, cA);                           \
    aD##PB = __builtin_elementwise_max(aD##PB, cB);                           \
}

#define COLOFF(J)                                                             \
    if (edge) {                                                               \
        const int col = x + (J) - 6;                                          \
        vld = (unsigned)col < (unsigned)WW;                                   \
        const int cc = col < 0 ? 0 : (col > WW-1 ? WW-1 : col);               \
        off = cc - x;                      /* clamped (safe) offset */        \
    } else { off = (J) - 6; vld = true; }

// ---- one source row (compile-time RYY): runtime 13-column loop (kept rolled
// for I-cache), prefetch-1 rotation, then the site's valid pair/quad-evals.
#define ROW_SITE(RYY, ...) {                                                  \
    const int sy = y0 + (RYY);                                                \
    if ((unsigned)sy < (unsigned)HH) {     /* uniform; skip = zero pad */     \
        const int rb = sy*WW + x;                                             \
        const float* __restrict__ pd = dP + rb;                               \
        const float* __restrict__ p0 = c0 + rb;                               \
        const float* __restrict__ p1 = c1 + rb;                               \
        const float* __restrict__ p2 = c2 + rb;                               \
        int off; bool vld;                                                    \
        COLOFF(0)                                                             \
        float dcur = pd[off], c0v = p0[off], c1v = p1[off], c2v = p2[off];    \
        if (!vld) dcur = 0.0f;             /* OOB col: w<=3.4e-4, no circle */\
        _Pragma("nounroll")                                                   \
        for (int j = 0; j < 13; ++j) {                                        \
            const int jn = j < 12 ? j + 1 : 12;                               \
            COLOFF(jn)                                                        \
            float dn = pd[off], n0 = p0[off], n1 = p1[off], n2 = p2[off];     \
            if (!vld) dn = 0.0f;                                              \
            const float v0 = c0v, v1 = c1v, v2 = c2v;                         \
            const float r  = fabsf(dcur);                                     \
            const float rr = fmaxf(dcur*dcur, 1.0f);                          \
            const float rc = rr * __builtin_amdgcn_exp2f(r*(float)(-KSIG));   \
            const float di = truncf(dcur); /* == (float)(int)defocus */       \
            const int ax = j < 6 ? 6 - j : j - 6;                             \
            const float4* __restrict__ tp = (const float4*)T4 + ax;           \
            __VA_ARGS__                                                       \
            dcur = dn; c0v = n0; c1v = n1; c2v = n2;                          \
        }                                                                     \
    }                                                                         \
}

#define WOUT(P) {                                                             \
    const float ix = __builtin_amdgcn_rcpf(aW##P.x);  /* aW >= ~0.01 */       \
    const float iy = __builtin_amdgcn_rcpf(aW##P.y);                          \
    const int yA = y0 + 2*(P), yB = yA + 1;                                   \
    const size_t oA = (size_t)yA*WW + x, oB = (size_t)yB*WW + x;              \
    out[(size_t)(b*3+0)*HWSZ + oA] = aR##P.x*ix;                              \
    out[(size_t)(b*3+1)*HWSZ + oA] = aG##P.x*ix;                              \
    out[(size_t)(b*3+2)*HWSZ + oA] = aB##P.x*ix;                              \
    out[DD_OFF + (size_t)b*HWSZ + oA] = aD##P.x;                              \
    out[(size_t)(b*3+0)*HWSZ + oB] = aR##P.y*iy;                              \
    out[(size_t)(b*3+1)*HWSZ + oB] = aG##P.y*iy;                              \
    out[(size_t)(b*3+2)*HWSZ + oB] = aB##P.y*iy;                              \
    out[DD_OFF + (size_t)b*HWSZ + oB] = aD##P.y;                              \
}

__global__ __launch_bounds__(256, 4)
void bokeh_kernel(const float* __restrict__ img,
                  const float* __restrict__ defo,
                  float* __restrict__ out)
{
    // T4[m+6][ax] = (D(|m|,ax), D(|m-1|,ax), C(|m|,ax), C(|m-1|,ax)).
    // D = fl32(sqrt(ay^2+ax^2)) correctly rounded (fp64), C = 2^(K*D).
    // Dead halves (ay>6 or ay^2+ax^2>49): (1e30, +inf) -> w~0, never in-circle.
    __shared__ float4 T4[14][7];
    {
        const int t = threadIdx.x;
        if (t < 14*7) {
            const int mi = t / 7, ax = t - mi*7;
            const int m  = mi - 6;
            const int a0 = m < 0 ? -m : m;
            const int a1 = (m-1) < 0 ? -(m-1) : (m-1);
            float D0 = 1e30f, C0 = __builtin_inff();
            float D1 = 1e30f, C1 = __builtin_inff();
            if (a0 <= 6 && a0*a0 + ax*ax <= 49) {
                D0 = (float)sqrt((double)(a0*a0 + ax*ax));
                C0 = (float)exp2((double)D0 * KSIG);
            }
            if (a1 <= 6 && a1*a1 + ax*ax <= 49) {
                D1 = (float)sqrt((double)(a1*a1 + ax*ax));
                C1 = (float)exp2((double)D1 * KSIG);
            }
            T4[mi][ax] = make_float4(D0, D1, C0, C1);
        }
    }
    __syncthreads();

    const int lane = threadIdx.x & 63;
    const int wv   = threadIdx.x >> 6;
    const int bx   = blockIdx.x;
    const int x    = bx*64 + lane;                 // lane = x -> coalesced
    const int y0   = blockIdx.y*32 + wv*8;         // 8 output rows per thread
    const int b    = blockIdx.z;
    const bool edge = (bx == 0) || (bx == WW/64 - 1);   // wave-uniform

    const float* __restrict__ dP = defo + (size_t)b*HWSZ;
    const float* __restrict__ c0 = img + (size_t)(b*3+0)*HWSZ;
    const float* __restrict__ c1 = img + (size_t)(b*3+1)*HWSZ;
    const float* __restrict__ c2 = img + (size_t)(b*3+2)*HWSZ;

    // named accumulators only -- no arrays, no address-taken (R8/R9 lesson)
    v2f aW0={0,0}, aW1={0,0}, aW2={0,0}, aW3={0,0};
    v2f aR0={0,0}, aR1={0,0}, aR2={0,0}, aR3={0,0};
    v2f aG0={0,0}, aG1={0,0}, aG2={0,0}, aG3={0,0};
    v2f aB0={0,0}, aB1={0,0}, aB2={0,0}, aB3={0,0};
    v2f aD0={-1e30f,-1e30f}, aD1={-1e30f,-1e30f};
    v2f aD2={-1e30f,-1e30f}, aD3={-1e30f,-1e30f};

    ROW_SITE(-6, PEVAL(0,0))
    ROW_SITE(-5, PEVAL(0,1))
    ROW_SITE(-4, QEVAL(0,1, 2,0))
    ROW_SITE(-3, QEVAL(0,1, 3,1))
    ROW_SITE(-2, QEVAL(0,1, 4,2)   PEVAL(2,0))
    ROW_SITE(-1, QEVAL(0,1, 5,3)   PEVAL(2,1))
    ROW_SITE( 0, QEVAL(0,1, 6,4)   QEVAL(2,3, 2,0))
    ROW_SITE( 1, QEVAL(0,1, 7,5)   QEVAL(2,3, 3,1))
    ROW_SITE( 2, QEVAL(0,1, 8,6)   QEVAL(2,3, 4,2))
    ROW_SITE( 3, QEVAL(0,1, 9,7)   QEVAL(2,3, 5,3))
    ROW_SITE( 4, QEVAL(0,1, 10,8)  QEVAL(2,3, 6,4))
    ROW_SITE( 5, QEVAL(0,1, 11,9)  QEVAL(2,3, 7,5))
    ROW_SITE( 6, QEVAL(0,1, 12,10) QEVAL(2,3, 8,6))
    ROW_SITE( 7, QEVAL(0,1, 13,11) QEVAL(2,3, 9,7))
    ROW_SITE( 8, PEVAL(1,12)       QEVAL(2,3, 10,8))
    ROW_SITE( 9, PEVAL(1,13)       QEVAL(2,3, 11,9))
    ROW_SITE(10,                   QEVAL(2,3, 12,10))
    ROW_SITE(11,                   QEVAL(2,3, 13,11))
    ROW_SITE(12,                   PEVAL(3,12))
    ROW_SITE(13,                   PEVAL(3,13))

    WOUT(0) WOUT(1) WOUT(2) WOUT(3)
}

extern "C" void kernel_launch(void* const* d_in, const int* in_sizes, int n_in,
                              void* d_out, int out_size, void* d_ws, size_t ws_size,
                              hipStream_t stream)
{
    const float* img  = (const float*)d_in[0];
    const float* defo = (const float*)d_in[1];
    float* out = (float*)d_out;
    bokeh_kernel<<<dim3(WW/64, HH/32, BB), dim3(256,1,1), 0, stream>>>(img, defo, out);
}

// Round 12
// 159.243 us; speedup vs baseline: 1.0580x; 1.0580x over previous
//
#include <hip/hip_runtime.h>
#include <math.h>

#define HH 512
#define WW 1024
#define HWSZ (HH*WW)
#define BB 4
#define KSIG 11.541560327111707
#define DD_OFF (BB*3*HWSZ)

typedef float v2f __attribute__((ext_vector_type(2)));

// ---- pair-eval: output-row pair P vs current source; MI = table row index
// (compile-time) -> ds_read_b128 at uniform addr + imm offset (broadcast).
// dd via arithmetic mask: mdi = min(r-D,0)*1e31 + di
//   r>=D  -> exactly di (reference-exact compare on correctly-rounded D)
//   r< D  -> <= -1e24 (live |r-D| >= ~4.8e-7), sentinel -> -inf; max ignores.
#define PEVAL(P, MI) {                                                        \
    const float4 t = tp[(MI)*7];            /* (D0,D1,C0,C1) */               \
    v2f den = (v2f){t.z, t.w} * rc + rr;    /* v_pk_fma_f32 */                \
    v2f w = { __builtin_amdgcn_rcpf(den.x),                                   \
              __builtin_amdgcn_rcpf(den.y) };                                 \
    aW##P += w;                                                               \
    aR##P += w * v0;  aG##P += w * v1;  aB##P += w * v2;                      \
    v2f rd = (v2f){r, r} - (v2f){t.x, t.y};                                   \
    v2f mdi = __builtin_elementwise_min(rd, (v2f){0.f, 0.f}) * 1e31f + di;    \
    aD##P = __builtin_elementwise_max(aD##P, mdi);                            \
}

// ---- one source row (compile-time RYY) inside the column loop. Clamped-row
// load + cndmask-to-zero keeps zero-pad semantics branchlessly (d=0 => w
// negligible, and every d=0-maskable slot has D>=1 => dd masked).
#define ROWV(RYY, ...) {                                                      \
    const int sy  = y0 + (RYY);                                               \
    const int scl = sy < 0 ? 0 : (sy > HH-1 ? HH-1 : sy);                     \
    const bool rv = (unsigned)sy < (unsigned)HH;                              \
    const int rb  = scl*WW + xoff;                                            \
    float dv = dP[rb];                                                        \
    const float v0 = c0[rb], v1 = c1[rb], v2 = c2[rb];                        \
    dv = (rv && vld) ? dv : 0.0f;                                             \
    const float r  = fabsf(dv);                                               \
    const float rr = fmaxf(dv*dv, 1.0f);                                      \
    const float rc = rr * __builtin_amdgcn_exp2f(r*(float)(-KSIG));           \
    const float di = truncf(dv);             /* == (float)(int)defocus */     \
    __VA_ARGS__                                                               \
}

#define WOUT(P) {                                                             \
    const float ix = __builtin_amdgcn_rcpf(aW##P.x);  /* aW >= ~0.01 */       \
    const float iy = __builtin_amdgcn_rcpf(aW##P.y);                          \
    const int yA = y0 + 2*(P), yB = yA + 1;                                   \
    const size_t oA = (size_t)yA*WW + x, oB = (size_t)yB*WW + x;              \
    out[(size_t)(b*3+0)*HWSZ + oA] = aR##P.x*ix;                              \
    out[(size_t)(b*3+1)*HWSZ + oA] = aG##P.x*ix;                              \
    out[(size_t)(b*3+2)*HWSZ + oA] = aB##P.x*ix;                              \
    out[DD_OFF + (size_t)b*HWSZ + oA] = aD##P.x;                              \
    out[(size_t)(b*3+0)*HWSZ + oB] = aR##P.y*iy;                              \
    out[(size_t)(b*3+1)*HWSZ + oB] = aG##P.y*iy;                              \
    out[(size_t)(b*3+2)*HWSZ + oB] = aB##P.y*iy;                              \
    out[DD_OFF + (size_t)b*HWSZ + oB] = aD##P.y;                              \
}

__global__ __launch_bounds__(256, 4)
void bokeh_kernel(const float* __restrict__ img,
                  const float* __restrict__ defo,
                  float* __restrict__ out)
{
    // T4[m+6][ax] = (D(|m|,ax), D(|m-1|,ax), C(|m|,ax), C(|m-1|,ax)).
    // D = fl32(sqrt(ay^2+ax^2)) correctly rounded (fp64), C = 2^(K*D).
    // Dead halves (ay>6 or ay^2+ax^2>49): (1e30, +inf) -> w~0, never in-circle.
    __shared__ float4 T4[14][7];
    {
        const int t = threadIdx.x;
        if (t < 14*7) {
            const int mi = t / 7, ax = t - mi*7;
            const int m  = mi - 6;
            const int a0 = m < 0 ? -m : m;
            const int a1 = (m-1) < 0 ? -(m-1) : (m-1);
            float D0 = 1e30f, C0 = __builtin_inff();
            float D1 = 1e30f, C1 = __builtin_inff();
            if (a0 <= 6 && a0*a0 + ax*ax <= 49) {
                D0 = (float)sqrt((double)(a0*a0 + ax*ax));
                C0 = (float)exp2((double)D0 * KSIG);
            }
            if (a1 <= 6 && a1*a1 + ax*ax <= 49) {
                D1 = (float)sqrt((double)(a1*a1 + ax*ax));
                C1 = (float)exp2((double)D1 * KSIG);
            }
            T4[mi][ax] = make_float4(D0, D1, C0, C1);
        }
    }
    __syncthreads();

    const int lane = threadIdx.x & 63;
    const int wv   = threadIdx.x >> 6;
    const int bx   = blockIdx.x;
    const int x    = bx*64 + lane;                 // lane = x -> coalesced
    const int y0   = blockIdx.y*32 + wv*8;         // 8 output rows per thread
    const int b    = blockIdx.z;
    const bool edge = (bx == 0) || (bx == WW/64 - 1);   // wave-uniform

    const float* __restrict__ dP = defo + (size_t)b*HWSZ;
    const float* __restrict__ c0 = img + (size_t)(b*3+0)*HWSZ;
    const float* __restrict__ c1 = img + (size_t)(b*3+1)*HWSZ;
    const float* __restrict__ c2 = img + (size_t)(b*3+2)*HWSZ;

    // named accumulators only -- no arrays, no address-taken (R8/R9 lesson)
    v2f aW0={0,0}, aW1={0,0}, aW2={0,0}, aW3={0,0};
    v2f aR0={0,0}, aR1={0,0}, aR2={0,0}, aR3={0,0};
    v2f aG0={0,0}, aG1={0,0}, aG2={0,0}, aG3={0,0};
    v2f aB0={0,0}, aB1={0,0}, aB2={0,0}, aB3={0,0};
    v2f aD0={-1e30f,-1e30f}, aD1={-1e30f,-1e30f};
    v2f aD2={-1e30f,-1e30f}, aD3={-1e30f,-1e30f};

#pragma nounroll
    for (int j = 0; j < 13; ++j) {                 // source columns (rolled)
        int xoff; bool vld;
        if (edge) {
            const int col = x + j - 6;
            vld  = (unsigned)col < (unsigned)WW;
            xoff = col < 0 ? 0 : (col > WW-1 ? WW-1 : col);  // clamped col
        } else { xoff = x + j - 6; vld = true; }
        const int ax = j < 6 ? 6 - j : j - 6;      // uniform
        const float4* __restrict__ tp = (const float4*)T4 + ax;

        ROWV(-6, PEVAL(0,0))
        ROWV(-5, PEVAL(0,1))
        ROWV(-4, PEVAL(0,2)  PEVAL(1,0))
        ROWV(-3, PEVAL(0,3)  PEVAL(1,1))
        ROWV(-2, PEVAL(0,4)  PEVAL(1,2)  PEVAL(2,0))
        ROWV(-1, PEVAL(0,5)  PEVAL(1,3)  PEVAL(2,1))
        ROWV( 0, PEVAL(0,6)  PEVAL(1,4)  PEVAL(2,2)  PEVAL(3,0))
        ROWV( 1, PEVAL(0,7)  PEVAL(1,5)  PEVAL(2,3)  PEVAL(3,1))
        ROWV( 2, PEVAL(0,8)  PEVAL(1,6)  PEVAL(2,4)  PEVAL(3,2))
        ROWV( 3, PEVAL(0,9)  PEVAL(1,7)  PEVAL(2,5)  PEVAL(3,3))
        ROWV( 4, PEVAL(0,10) PEVAL(1,8)  PEVAL(2,6)  PEVAL(3,4))
        ROWV( 5, PEVAL(0,11) PEVAL(1,9)  PEVAL(2,7)  PEVAL(3,5))
        ROWV( 6, PEVAL(0,12) PEVAL(1,10) PEVAL(2,8)  PEVAL(3,6))
        ROWV( 7, PEVAL(0,13) PEVAL(1,11) PEVAL(2,9)  PEVAL(3,7))
        ROWV( 8,             PEVAL(1,12) PEVAL(2,10) PEVAL(3,8))
        ROWV( 9,             PEVAL(1,13) PEVAL(2,11) PEVAL(3,9))
        ROWV(10,                         PEVAL(2,12) PEVAL(3,10))
        ROWV(11,                         PEVAL(2,13) PEVAL(3,11))
        ROWV(12,                                     PEVAL(3,12))
        ROWV(13,                                     PEVAL(3,13))
    }

    WOUT(0) WOUT(1) WOUT(2) WOUT(3)
}

extern "C" void kernel_launch(void* const* d_in, const int* in_sizes, int n_in,
                              void* d_out, int out_size, void* d_ws, size_t ws_size,
                              hipStream_t stream)
{
    const float* img  = (const float*)d_in[0];
    const float* defo = (const float*)d_in[1];
    float* out = (float*)d_out;
    bokeh_kernel<<<dim3(WW/64, HH/32, BB), dim3(256,1,1), 0, stream>>>(img, defo, out);
}